// Round 1
// baseline (59.457 us; speedup 1.0000x reference)
//
#include <hip/hip_runtime.h>
#include <math.h>

#define N_PTS 65536
#define N_CTR 1024

#if __has_builtin(__builtin_amdgcn_exp2f)
#define EXP2(x) __builtin_amdgcn_exp2f(x)
#else
#define EXP2(x) exp2f(x)
#endif

// Per-block LDS: 1024 x float4 (cx, cy, -d1*log2e, -d2*log2e) = 16 KB
//              + 1024 x float2 (set-specific coefficients)      =  8 KB
// Total 24 KB -> up to 6 blocks/CU by LDS; grid gives 3 blocks/CU (12 waves).
__global__ __launch_bounds__(256) void srbf_kernel(
    const float* __restrict__ x,
    const float* __restrict__ h0, const float* __restrict__ c0, const float* __restrict__ w0,
    const float* __restrict__ h1, const float* __restrict__ c1, const float* __restrict__ w1,
    const float* __restrict__ h2, const float* __restrict__ c2, const float* __restrict__ w2,
    float* __restrict__ out)
{
    __shared__ float4 s4[N_CTR];
    __shared__ float2 s2[N_CTR];

    const int set = blockIdx.x >> 8;   // 0,1,2 — 256 blocks per set
    const int blk = blockIdx.x & 255;
    const int tid = threadIdx.x;

    const float* __restrict__ h = (set == 0) ? h0 : ((set == 1) ? h1 : h2);
    const float2* __restrict__ c = (const float2*)((set == 0) ? c0 : ((set == 1) ? c1 : c2));
    const float2* __restrict__ w = (const float2*)((set == 0) ? w0 : ((set == 1) ? w1 : w2));

    const float LOG2E = 1.4426950408889634f;

    // Stage pre-folded per-center constants into LDS (4 centers/thread).
    for (int j = tid; j < N_CTR; j += 256) {
        float2 cj = c[j];
        float2 wj = w[j];
        float hh = h[j];
        float d1 = wj.x * wj.x;
        float d2 = wj.y * wj.y;
        s4[j] = make_float4(cj.x, cj.y, -d1 * LOG2E, -d2 * LOG2E);
        float a, b;
        if (set == 0)      { a = -2.f * hh * d1; b = -2.f * hh * d2; }  // ux, uy
        else if (set == 1) { a = hh;             b = -2.f * hh * d1; }  // P, Px
        else               { a = hh;             b = -2.f * hh * d2; }  // Q, Qy
        s2[j] = make_float2(a, b);
    }
    __syncthreads();

    const int i = (blk << 8) + tid;
    const float2 xy = ((const float2*)x)[i];
    const float xi = xy.x, yi = xy.y;

    float acc0 = 0.f, acc1 = 0.f;

    if (set == 0) {
        #pragma unroll 8
        for (int j = 0; j < N_CTR; ++j) {
            float4 v = s4[j];
            float2 g = s2[j];
            float dx = xi - v.x, dy = yi - v.y;
            float s = fmaf(dy * dy, v.w, dx * dx * v.z);
            float e = EXP2(s);
            acc0 = fmaf(dx * g.x, e, acc0);   // ux = sum(dx * (-2 h d1) * e)
            acc1 = fmaf(dy * g.y, e, acc1);   // uy = sum(dy * (-2 h d2) * e)
        }
    } else if (set == 1) {
        #pragma unroll 8
        for (int j = 0; j < N_CTR; ++j) {
            float4 v = s4[j];
            float2 g = s2[j];
            float dx = xi - v.x, dy = yi - v.y;
            float s = fmaf(dy * dy, v.w, dx * dx * v.z);
            float e = EXP2(s);
            acc0 = fmaf(g.x, e, acc0);        // P  = sum(h * e)
            acc1 = fmaf(dx * g.y, e, acc1);   // Px = sum(dx * (-2 h d1) * e)
        }
    } else {
        #pragma unroll 8
        for (int j = 0; j < N_CTR; ++j) {
            float4 v = s4[j];
            float2 g = s2[j];
            float dx = xi - v.x, dy = yi - v.y;
            float s = fmaf(dy * dy, v.w, dx * dx * v.z);
            float e = EXP2(s);
            acc0 = fmaf(g.x, e, acc0);        // Q  = sum(h * e)
            acc1 = fmaf(dy * g.y, e, acc1);   // Qy = sum(dy * (-2 h d2) * e)
        }
    }

    float* o = out + (size_t)set * 2 * N_PTS;
    o[i] = acc0;
    o[N_PTS + i] = acc1;
}

extern "C" void kernel_launch(void* const* d_in, const int* in_sizes, int n_in,
                              void* d_out, int out_size, void* d_ws, size_t ws_size,
                              hipStream_t stream) {
    const float* x  = (const float*)d_in[0];
    const float* h1 = (const float*)d_in[1];
    const float* c1 = (const float*)d_in[2];
    const float* w1 = (const float*)d_in[3];
    const float* h2 = (const float*)d_in[4];
    const float* c2 = (const float*)d_in[5];
    const float* w2 = (const float*)d_in[6];
    const float* h3 = (const float*)d_in[7];
    const float* c3 = (const float*)d_in[8];
    const float* w3 = (const float*)d_in[9];

    srbf_kernel<<<dim3(3 * 256), dim3(256), 0, stream>>>(
        x, h1, c1, w1, h2, c2, w2, h3, c3, w3, (float*)d_out);
}